// Round 1
// baseline (192.226 us; speedup 1.0000x reference)
//
#include <hip/hip_runtime.h>
#include <math.h>

// NoisyTopKRouter: x[T,2048] @ {W_route,W_noise}[2048,64] (+biases),
// noisy = r + eps*softplus(nr); top-2 over 64 experts; softmax of top-2
// scattered into zeros[T,64]; idx[T,2] written as float values.
// T = 16384 (B=4, S=4096), n_embd = 2048, E = 64.

#define BM 64    // tokens per block
#define BN 128   // 64 route logits + 64 noise logits
#define BK 32    // k-chunk
#define NEMBD 2048
#define NEXP 64

__global__ __launch_bounds__(256) void noisy_topk_router_kernel(
    const float* __restrict__ x,     // [T, 2048]
    const float* __restrict__ eps,   // [T, 64]
    const float* __restrict__ Wr,    // [2048, 64]
    const float* __restrict__ br,    // [64]
    const float* __restrict__ Wn,    // [2048, 64]
    const float* __restrict__ bn,    // [64]
    float* __restrict__ out_r,       // [T, 64]
    float* __restrict__ out_idx)     // [T, 2] (float-encoded ints)
{
    __shared__ float xs[BK][BM];     // 8 KB, transposed x tile
    __shared__ float ws[BK][BN];     // 16 KB, [route | noise] rows
    __shared__ float lg[BN][BM];     // 32 KB, logits transposed
    __shared__ float tk[4][BM];      // p1, p2, i1, i2 per token

    const int tid = threadIdx.x;
    const int tx  = tid & 15;        // output-column group (8 outputs each)
    const int ty  = tid >> 4;        // token-row group (4 tokens each)
    const int m0  = blockIdx.x * BM;

    float acc[4][8];
    #pragma unroll
    for (int i = 0; i < 4; ++i)
        #pragma unroll
        for (int j = 0; j < 8; ++j) acc[i][j] = 0.f;

    // ---- main K loop ----
    for (int kc = 0; kc < NEMBD; kc += BK) {
        // stage x tile: thread loads 8 consecutive floats of one token row,
        // stores transposed into xs[k][m]
        {
            const int tm = tid >> 2;            // 0..63 token
            const int kk = (tid & 3) << 3;      // 0,8,16,24
            const float* src = x + (size_t)(m0 + tm) * NEMBD + kc + kk;
            const float4 a = *(const float4*)(src);
            const float4 b = *(const float4*)(src + 4);
            xs[kk + 0][tm] = a.x; xs[kk + 1][tm] = a.y;
            xs[kk + 2][tm] = a.z; xs[kk + 3][tm] = a.w;
            xs[kk + 4][tm] = b.x; xs[kk + 5][tm] = b.y;
            xs[kk + 6][tm] = b.z; xs[kk + 7][tm] = b.w;
        }
        // stage W tile: row kr of [route(64) | noise(64)]; thread loads 16 floats
        {
            const int kr = tid >> 3;            // 0..31
            const int q  = tid & 7;             // 0..7 ; q<4 route, q>=4 noise
            const float* src = (q < 4)
                ? (Wr + (size_t)(kc + kr) * NEXP + (q << 4))
                : (Wn + (size_t)(kc + kr) * NEXP + ((q - 4) << 4));
            const float4 a = *(const float4*)(src + 0);
            const float4 b = *(const float4*)(src + 4);
            const float4 c = *(const float4*)(src + 8);
            const float4 d = *(const float4*)(src + 12);
            float* dst = &ws[kr][q << 4];
            *(float4*)(dst + 0)  = a;
            *(float4*)(dst + 4)  = b;
            *(float4*)(dst + 8)  = c;
            *(float4*)(dst + 12) = d;
        }
        __syncthreads();

        #pragma unroll
        for (int k = 0; k < BK; ++k) {
            const float4 xv = *(const float4*)&xs[k][ty << 2];
            const float4 wa = *(const float4*)&ws[k][tx << 3];
            const float4 wb = *(const float4*)&ws[k][(tx << 3) + 4];
            const float xr[4] = {xv.x, xv.y, xv.z, xv.w};
            const float wc[8] = {wa.x, wa.y, wa.z, wa.w, wb.x, wb.y, wb.z, wb.w};
            #pragma unroll
            for (int i = 0; i < 4; ++i)
                #pragma unroll
                for (int j = 0; j < 8; ++j)
                    acc[i][j] = fmaf(xr[i], wc[j], acc[i][j]);
        }
        __syncthreads();
    }

    // ---- epilogue: bias add, store logits transposed ----
    {
        const int n0 = tx << 3;
        #pragma unroll
        for (int j = 0; j < 8; ++j) {
            const int n = n0 + j;
            const float b = (n < NEXP) ? br[n] : bn[n - NEXP];
            #pragma unroll
            for (int i = 0; i < 4; ++i)
                lg[n][(ty << 2) + i] = acc[i][j] + b;
        }
    }
    __syncthreads();

    // ---- top-2 per token (threads 0..63) ----
    if (tid < BM) {
        const int t = tid;
        const float* ep = eps + (size_t)(m0 + t) * NEXP;
        float v1 = -1e30f, v2 = -1e30f;
        int i1 = 0, i2 = 0;
        for (int e = 0; e < NEXP; ++e) {
            const float r  = lg[e][t];
            const float nr = lg[NEXP + e][t];
            // softplus(nr) = max(nr,0) + log1p(exp(-|nr|))
            const float sp = fmaxf(nr, 0.f) + log1pf(expf(-fabsf(nr)));
            const float noisy = fmaf(ep[e], sp, r);
            if (noisy > v1) { v2 = v1; i2 = i1; v1 = noisy; i1 = e; }
            else if (noisy > v2) { v2 = noisy; i2 = e; }
        }
        const float e2 = expf(v2 - v1);
        const float p1 = 1.f / (1.f + e2);
        const float p2 = e2 * p1;
        tk[0][t] = p1; tk[1][t] = p2;
        tk[2][t] = (float)i1; tk[3][t] = (float)i2;
    }
    __syncthreads();

    // ---- write r_out: 4 threads per token, 16 floats each, coalesced ----
    {
        const int t = tid >> 2;
        const int c = tid & 3;
        const float p1 = tk[0][t], p2 = tk[1][t];
        const int i1 = (int)tk[2][t], i2 = (int)tk[3][t];
        float buf[16];
        #pragma unroll
        for (int j = 0; j < 16; ++j) {
            const int e = (c << 4) + j;
            buf[j] = (e == i1) ? p1 : (e == i2) ? p2 : 0.f;
        }
        float* dst = out_r + (size_t)(m0 + t) * NEXP + (c << 4);
        *(float4*)(dst + 0)  = *(float4*)(buf + 0);
        *(float4*)(dst + 4)  = *(float4*)(buf + 4);
        *(float4*)(dst + 8)  = *(float4*)(buf + 8);
        *(float4*)(dst + 12) = *(float4*)(buf + 12);
    }
    // ---- write idx (as floats) ----
    if (tid < BM) {
        float2 v = make_float2(tk[2][tid], tk[3][tid]);
        *(float2*)(out_idx + (size_t)(m0 + tid) * 2) = v;
    }
}

extern "C" void kernel_launch(void* const* d_in, const int* in_sizes, int n_in,
                              void* d_out, int out_size, void* d_ws, size_t ws_size,
                              hipStream_t stream) {
    const float* x  = (const float*)d_in[0];
    const float* ep = (const float*)d_in[1];
    const float* Wr = (const float*)d_in[2];
    const float* br = (const float*)d_in[3];
    const float* Wn = (const float*)d_in[4];
    const float* bn = (const float*)d_in[5];

    const int T = in_sizes[1] / NEXP;   // tokens from noise_eps element count
    float* out_r   = (float*)d_out;
    float* out_idx = (float*)d_out + (size_t)T * NEXP;

    dim3 grid(T / BM), block(256);
    noisy_topk_router_kernel<<<grid, block, 0, stream>>>(
        x, ep, Wr, br, Wn, bn, out_r, out_idx);
}

// Round 2
// 146.692 us; speedup vs baseline: 1.3104x; 1.3104x over previous
//
#include <hip/hip_runtime.h>
#include <math.h>

// NoisyTopKRouter, split-K two-kernel version.
// x[T,2048] @ [Wr|Wn][2048,64] -> logits[T,128] (split over K into d_ws),
// then reduce + bias + softplus-noise + top-2 + softmax-scatter.
// T = 16384, n_embd = 2048, E = 64.

#define NEMBD 2048
#define NEXP  64
#define BM    64
#define BK    32

// ---------------- Kernel 1: partial GEMM (split-K) ----------------
__global__ __launch_bounds__(256, 4) void router_gemm_partial(
    const float* __restrict__ x,    // [T, 2048]
    const float* __restrict__ Wr,   // [2048, 64]
    const float* __restrict__ Wn,   // [2048, 64]
    float* __restrict__ part,       // [ksplit, T, 128]
    int T, int ksplit)
{
    __shared__ float xs[BM][BK + 4];     // [64][36] un-transposed, padded
    __shared__ float ws[BK][128 + 4];    // [32][132] padded

    const int tid = threadIdx.x;
    const int tx = tid & 15;             // expert-col group (8 cols)
    const int ty = tid >> 4;             // token group (4 tokens)
    const int m0 = blockIdx.x * BM;
    const int kz = blockIdx.y;
    const int klen = NEMBD / ksplit;
    const int k0 = kz * klen;

    float acc[4][8];
    #pragma unroll
    for (int i = 0; i < 4; ++i)
        #pragma unroll
        for (int j = 0; j < 8; ++j) acc[i][j] = 0.f;

    for (int kc = 0; kc < klen; kc += BK) {
        // stage x tile: thread -> 8 consecutive k of one token, b128 stores
        {
            const int tm = tid >> 2;            // 0..63
            const int kk = (tid & 3) << 3;      // 0,8,16,24
            const float* src = x + (size_t)(m0 + tm) * NEMBD + k0 + kc + kk;
            const float4 a = *(const float4*)(src);
            const float4 b = *(const float4*)(src + 4);
            *(float4*)&xs[tm][kk]     = a;
            *(float4*)&xs[tm][kk + 4] = b;
        }
        // stage W tile: row kr of [route(64) | noise(64)], b128 stores
        {
            const int kr = tid >> 3;            // 0..31
            const int q  = tid & 7;             // 0..7; q<4 route, q>=4 noise
            const float* src = (q < 4)
                ? (Wr + (size_t)(k0 + kc + kr) * NEXP + (q << 4))
                : (Wn + (size_t)(k0 + kc + kr) * NEXP + ((q - 4) << 4));
            const float4 a = *(const float4*)(src + 0);
            const float4 b = *(const float4*)(src + 4);
            const float4 c = *(const float4*)(src + 8);
            const float4 d = *(const float4*)(src + 12);
            float* dst = &ws[kr][q << 4];
            *(float4*)(dst + 0)  = a;
            *(float4*)(dst + 4)  = b;
            *(float4*)(dst + 8)  = c;
            *(float4*)(dst + 12) = d;
        }
        __syncthreads();

        #pragma unroll
        for (int k = 0; k < BK; ++k) {
            float xr[4];
            #pragma unroll
            for (int i = 0; i < 4; ++i) xr[i] = xs[(ty << 2) + i][k];
            const float4 wa = *(const float4*)&ws[k][tx << 3];
            const float4 wb = *(const float4*)&ws[k][(tx << 3) + 4];
            const float wc[8] = {wa.x, wa.y, wa.z, wa.w, wb.x, wb.y, wb.z, wb.w};
            #pragma unroll
            for (int i = 0; i < 4; ++i)
                #pragma unroll
                for (int j = 0; j < 8; ++j)
                    acc[i][j] = fmaf(xr[i], wc[j], acc[i][j]);
        }
        __syncthreads();
    }

    // write partials [kz][token][128]
    float* dst = part + ((size_t)kz * T + m0) * 128;
    #pragma unroll
    for (int i = 0; i < 4; ++i) {
        const int t = (ty << 2) + i;
        float4 lo = make_float4(acc[i][0], acc[i][1], acc[i][2], acc[i][3]);
        float4 hi = make_float4(acc[i][4], acc[i][5], acc[i][6], acc[i][7]);
        *(float4*)(dst + (size_t)t * 128 + (tx << 3))     = lo;
        *(float4*)(dst + (size_t)t * 128 + (tx << 3) + 4) = hi;
    }
}

// ---------------- Kernel 2: reduce + bias + top-2 + scatter ----------------
__global__ __launch_bounds__(256) void router_epilogue(
    const float* __restrict__ part,  // [ksplit, T, 128]
    const float* __restrict__ eps,   // [T, 64]
    const float* __restrict__ br,    // [64]
    const float* __restrict__ bn,    // [64]
    float* __restrict__ out_r,       // [T, 64]
    float* __restrict__ out_idx,     // [T, 2]
    int T, int ksplit)
{
    __shared__ float lg[128][BM + 1];    // logits transposed, padded
    __shared__ float tk[4][BM];

    const int tid = threadIdx.x;
    const int tx = tid & 15;
    const int ty = tid >> 4;
    const int m0 = blockIdx.x * BM;

    // reduce partials: thread owns 4 tokens x 8 cols
    float4 s[8];
    #pragma unroll
    for (int i = 0; i < 8; ++i) s[i] = make_float4(0.f, 0.f, 0.f, 0.f);
    for (int kz = 0; kz < ksplit; ++kz) {
        const float* p = part + ((size_t)kz * T + m0) * 128;
        #pragma unroll
        for (int i = 0; i < 4; ++i) {
            const int t = (ty << 2) + i;
            const float4 lo = *(const float4*)(p + (size_t)t * 128 + (tx << 3));
            const float4 hi = *(const float4*)(p + (size_t)t * 128 + (tx << 3) + 4);
            s[2 * i].x += lo.x; s[2 * i].y += lo.y; s[2 * i].z += lo.z; s[2 * i].w += lo.w;
            s[2 * i + 1].x += hi.x; s[2 * i + 1].y += hi.y; s[2 * i + 1].z += hi.z; s[2 * i + 1].w += hi.w;
        }
    }
    // bias + store transposed
    {
        const int n0 = tx << 3;
        float bias[8];
        #pragma unroll
        for (int j = 0; j < 8; ++j) {
            const int n = n0 + j;
            bias[j] = (n < NEXP) ? br[n] : bn[n - NEXP];
        }
        #pragma unroll
        for (int i = 0; i < 4; ++i) {
            const int t = (ty << 2) + i;
            const float v[8] = {s[2*i].x, s[2*i].y, s[2*i].z, s[2*i].w,
                                s[2*i+1].x, s[2*i+1].y, s[2*i+1].z, s[2*i+1].w};
            #pragma unroll
            for (int j = 0; j < 8; ++j)
                lg[n0 + j][t] = v[j] + bias[j];
        }
    }
    __syncthreads();

    // top-2 per token (threads 0..63)
    if (tid < BM) {
        const int t = tid;
        const float* ep = eps + (size_t)(m0 + t) * NEXP;
        float v1 = -1e30f, v2 = -1e30f;
        int i1 = 0, i2 = 0;
        for (int e = 0; e < NEXP; ++e) {
            const float r  = lg[e][t];
            const float nr = lg[NEXP + e][t];
            const float sp = fmaxf(nr, 0.f) + log1pf(expf(-fabsf(nr)));
            const float noisy = fmaf(ep[e], sp, r);
            if (noisy > v1) { v2 = v1; i2 = i1; v1 = noisy; i1 = e; }
            else if (noisy > v2) { v2 = noisy; i2 = e; }
        }
        const float e2 = expf(v2 - v1);
        const float p1 = 1.f / (1.f + e2);
        const float p2 = e2 * p1;
        tk[0][t] = p1; tk[1][t] = p2;
        tk[2][t] = (float)i1; tk[3][t] = (float)i2;
    }
    __syncthreads();

    // write r_out coalesced
    {
        const int t = tid >> 2;
        const int c = tid & 3;
        const float p1 = tk[0][t], p2 = tk[1][t];
        const int i1 = (int)tk[2][t], i2 = (int)tk[3][t];
        float buf[16];
        #pragma unroll
        for (int j = 0; j < 16; ++j) {
            const int e = (c << 4) + j;
            buf[j] = (e == i1) ? p1 : (e == i2) ? p2 : 0.f;
        }
        float* dst = out_r + (size_t)(m0 + t) * NEXP + (c << 4);
        *(float4*)(dst + 0)  = *(float4*)(buf + 0);
        *(float4*)(dst + 4)  = *(float4*)(buf + 4);
        *(float4*)(dst + 8)  = *(float4*)(buf + 8);
        *(float4*)(dst + 12) = *(float4*)(buf + 12);
    }
    if (tid < BM) {
        float2 v = make_float2(tk[2][tid], tk[3][tid]);
        *(float2*)(out_idx + (size_t)(m0 + tid) * 2) = v;
    }
}

// ---------------- Fallback: original fused single kernel ----------------
__global__ __launch_bounds__(256) void noisy_topk_router_fused(
    const float* __restrict__ x, const float* __restrict__ eps,
    const float* __restrict__ Wr, const float* __restrict__ br,
    const float* __restrict__ Wn, const float* __restrict__ bn,
    float* __restrict__ out_r, float* __restrict__ out_idx)
{
    __shared__ float xs[BK][BM];
    __shared__ float ws[BK][128];
    __shared__ float lg[128][BM];
    __shared__ float tk[4][BM];

    const int tid = threadIdx.x;
    const int tx  = tid & 15;
    const int ty  = tid >> 4;
    const int m0  = blockIdx.x * BM;

    float acc[4][8];
    #pragma unroll
    for (int i = 0; i < 4; ++i)
        #pragma unroll
        for (int j = 0; j < 8; ++j) acc[i][j] = 0.f;

    for (int kc = 0; kc < NEMBD; kc += BK) {
        {
            const int tm = tid >> 2;
            const int kk = (tid & 3) << 3;
            const float* src = x + (size_t)(m0 + tm) * NEMBD + kc + kk;
            const float4 a = *(const float4*)(src);
            const float4 b = *(const float4*)(src + 4);
            xs[kk + 0][tm] = a.x; xs[kk + 1][tm] = a.y;
            xs[kk + 2][tm] = a.z; xs[kk + 3][tm] = a.w;
            xs[kk + 4][tm] = b.x; xs[kk + 5][tm] = b.y;
            xs[kk + 6][tm] = b.z; xs[kk + 7][tm] = b.w;
        }
        {
            const int kr = tid >> 3;
            const int q  = tid & 7;
            const float* src = (q < 4)
                ? (Wr + (size_t)(kc + kr) * NEXP + (q << 4))
                : (Wn + (size_t)(kc + kr) * NEXP + ((q - 4) << 4));
            const float4 a = *(const float4*)(src + 0);
            const float4 b = *(const float4*)(src + 4);
            const float4 c = *(const float4*)(src + 8);
            const float4 d = *(const float4*)(src + 12);
            float* dst = &ws[kr][q << 4];
            *(float4*)(dst + 0)  = a;
            *(float4*)(dst + 4)  = b;
            *(float4*)(dst + 8)  = c;
            *(float4*)(dst + 12) = d;
        }
        __syncthreads();
        #pragma unroll
        for (int k = 0; k < BK; ++k) {
            const float4 xv = *(const float4*)&xs[k][ty << 2];
            const float4 wa = *(const float4*)&ws[k][tx << 3];
            const float4 wb = *(const float4*)&ws[k][(tx << 3) + 4];
            const float xr[4] = {xv.x, xv.y, xv.z, xv.w};
            const float wc[8] = {wa.x, wa.y, wa.z, wa.w, wb.x, wb.y, wb.z, wb.w};
            #pragma unroll
            for (int i = 0; i < 4; ++i)
                #pragma unroll
                for (int j = 0; j < 8; ++j)
                    acc[i][j] = fmaf(xr[i], wc[j], acc[i][j]);
        }
        __syncthreads();
    }
    {
        const int n0 = tx << 3;
        #pragma unroll
        for (int j = 0; j < 8; ++j) {
            const int n = n0 + j;
            const float b = (n < NEXP) ? br[n] : bn[n - NEXP];
            #pragma unroll
            for (int i = 0; i < 4; ++i)
                lg[n][(ty << 2) + i] = acc[i][j] + b;
        }
    }
    __syncthreads();
    if (tid < BM) {
        const int t = tid;
        const float* ep = eps + (size_t)(m0 + t) * NEXP;
        float v1 = -1e30f, v2 = -1e30f;
        int i1 = 0, i2 = 0;
        for (int e = 0; e < NEXP; ++e) {
            const float r  = lg[e][t];
            const float nr = lg[NEXP + e][t];
            const float sp = fmaxf(nr, 0.f) + log1pf(expf(-fabsf(nr)));
            const float noisy = fmaf(ep[e], sp, r);
            if (noisy > v1) { v2 = v1; i2 = i1; v1 = noisy; i1 = e; }
            else if (noisy > v2) { v2 = noisy; i2 = e; }
        }
        const float e2 = expf(v2 - v1);
        const float p1 = 1.f / (1.f + e2);
        const float p2 = e2 * p1;
        tk[0][t] = p1; tk[1][t] = p2;
        tk[2][t] = (float)i1; tk[3][t] = (float)i2;
    }
    __syncthreads();
    {
        const int t = tid >> 2;
        const int c = tid & 3;
        const float p1 = tk[0][t], p2 = tk[1][t];
        const int i1 = (int)tk[2][t], i2 = (int)tk[3][t];
        float buf[16];
        #pragma unroll
        for (int j = 0; j < 16; ++j) {
            const int e = (c << 4) + j;
            buf[j] = (e == i1) ? p1 : (e == i2) ? p2 : 0.f;
        }
        float* dst = out_r + (size_t)(m0 + t) * NEXP + (c << 4);
        *(float4*)(dst + 0)  = *(float4*)(buf + 0);
        *(float4*)(dst + 4)  = *(float4*)(buf + 4);
        *(float4*)(dst + 8)  = *(float4*)(buf + 8);
        *(float4*)(dst + 12) = *(float4*)(buf + 12);
    }
    if (tid < BM) {
        float2 v = make_float2(tk[2][tid], tk[3][tid]);
        *(float2*)(out_idx + (size_t)(m0 + tid) * 2) = v;
    }
}

extern "C" void kernel_launch(void* const* d_in, const int* in_sizes, int n_in,
                              void* d_out, int out_size, void* d_ws, size_t ws_size,
                              hipStream_t stream) {
    const float* x  = (const float*)d_in[0];
    const float* ep = (const float*)d_in[1];
    const float* Wr = (const float*)d_in[2];
    const float* br = (const float*)d_in[3];
    const float* Wn = (const float*)d_in[4];
    const float* bn = (const float*)d_in[5];

    const int T = in_sizes[1] / NEXP;
    float* out_r   = (float*)d_out;
    float* out_idx = (float*)d_out + (size_t)T * NEXP;

    const size_t per = (size_t)T * 128 * sizeof(float);
    int ksplit = 0;
    if (ws_size >= 4 * per) ksplit = 4;
    else if (ws_size >= 2 * per) ksplit = 2;
    else if (ws_size >= per) ksplit = 1;

    if (ksplit > 0) {
        float* part = (float*)d_ws;
        dim3 g1(T / BM, ksplit), b1(256);
        router_gemm_partial<<<g1, b1, 0, stream>>>(x, Wr, Wn, part, T, ksplit);
        dim3 g2(T / BM), b2(256);
        router_epilogue<<<g2, b2, 0, stream>>>(part, ep, br, bn, out_r, out_idx, T, ksplit);
    } else {
        dim3 grid(T / BM), block(256);
        noisy_topk_router_fused<<<grid, block, 0, stream>>>(
            x, ep, Wr, br, Wn, bn, out_r, out_idx);
    }
}

// Round 3
// 76.121 us; speedup vs baseline: 2.5253x; 1.9271x over previous
//
#include <hip/hip_runtime.h>
#include <math.h>

// NoisyTopKRouter via f16 2-limb (Markidis) 3-pass MFMA, fully fused.
// logits = x[T,2048] @ [Wr|Wn][2048,64]*64 (limbs) / 64 + bias
// noisy = r + eps*softplus(nr); top-2; softmax-scatter; idx as floats.

typedef _Float16 f16;
typedef _Float16 f16x4 __attribute__((ext_vector_type(4)));
typedef _Float16 f16x8 __attribute__((ext_vector_type(8)));
typedef float    f32x4 __attribute__((ext_vector_type(4)));

#define NEMBD 2048
#define NEXP  64
#define BM    64
#define BK    32
#define NCH   (NEMBD / BK)    // 64 chunks
#define XP    40              // padded LDS row stride (f16) for x limbs
#define WP    40              // padded LDS row stride (f16) for w limbs
#define WSCALE 64.0f
#define INV_WSCALE 0.015625f

union F4H8 { float4 f; f16x8 h; };

// ---------- kernel 0: W -> transposed, x64-scaled f16 limbs ----------
// wt layout per limb: [chunk 64][n 128][k 32] f16 (n: 0..63 route, 64..127 noise)
__global__ __launch_bounds__(256) void build_wt(
    const float* __restrict__ Wr, const float* __restrict__ Wn,
    f16* __restrict__ wt_hi, f16* __restrict__ wt_lo)
{
    __shared__ float ws[BK][129];
    const int c = blockIdx.x, t = threadIdx.x;
    const int k0 = c * BK;
    {
        const int k  = t >> 3;
        const int n8 = (t & 7) << 3;
        const float* s0 = Wr + (size_t)(k0 + k) * NEXP + n8;
        const float* s1 = Wn + (size_t)(k0 + k) * NEXP + n8;
        #pragma unroll
        for (int j = 0; j < 8; ++j) ws[k][n8 + j] = s0[j];
        #pragma unroll
        for (int j = 0; j < 8; ++j) ws[k][64 + n8 + j] = s1[j];
    }
    __syncthreads();
    {
        const int n  = t >> 1;           // 0..127
        const int kh = (t & 1) << 4;     // 0 or 16
        f16x8 hv0, hv1, lv0, lv1;
        #pragma unroll
        for (int j = 0; j < 8; ++j) {
            const float v = ws[kh + j][n] * WSCALE;
            const f16 h = (f16)v;
            hv0[j] = h; lv0[j] = (f16)(v - (float)h);
        }
        #pragma unroll
        for (int j = 0; j < 8; ++j) {
            const float v = ws[kh + 8 + j][n] * WSCALE;
            const f16 h = (f16)v;
            hv1[j] = h; lv1[j] = (f16)(v - (float)h);
        }
        const size_t base = ((size_t)c * 128 + n) * 32 + kh;
        *(f16x8*)(wt_hi + base)     = hv0;
        *(f16x8*)(wt_hi + base + 8) = hv1;
        *(f16x8*)(wt_lo + base)     = lv0;
        *(f16x8*)(wt_lo + base + 8) = lv1;
    }
}

// ---------- kernel 1: fused MFMA router ----------
// grid T/64, 512 threads = 8 waves; wave (wr,wc): rows wr*32, cols wc*32
__global__ __launch_bounds__(512, 2) void router_fused(
    const float* __restrict__ x, const float* __restrict__ eps,
    const f16* __restrict__ wt_hi, const f16* __restrict__ wt_lo,
    const float* __restrict__ br, const float* __restrict__ bn,
    float* __restrict__ out_r, float* __restrict__ out_idx)
{
    __shared__ __align__(16) float smem_f[15360];          // 61440 B
    f16* XH = (f16*)smem_f;                                 // [2][64][XP]
    f16* XL = XH + 2 * 64 * XP;
    f16* WH = XL + 2 * 64 * XP;                             // [2][128][WP]
    f16* WL = WH + 2 * 128 * WP;
    float* LG = smem_f;                                     // [128][65] overlay
    float* TK = smem_f + 128 * 65;                          // [4][64]

    const int tid  = threadIdx.x;
    const int lane = tid & 63;
    const int w    = tid >> 6;
    const int wr   = w & 1, wc = w >> 1;
    const int m0   = blockIdx.x * BM;

    // staging mapping
    const int sxm = tid >> 3;                  // x row 0..63
    const int sxk = (tid & 7) << 2;            // k offset 0..28
    const float* xsrc = x + (size_t)(m0 + sxm) * NEMBD + sxk;
    const int xoff = sxm * XP + sxk;
    const int woff = (tid >> 2) * WP + ((tid & 3) << 3);

    // fragment mapping
    const int arow0 = wr * 32 + (lane & 15);
    const int bcol0 = wc * 32 + (lane & 15);
    const int kgrp  = (lane >> 4) << 3;

    f32x4 acc[2][2];
    #pragma unroll
    for (int i = 0; i < 2; ++i)
        #pragma unroll
        for (int j = 0; j < 2; ++j)
            acc[i][j] = (f32x4){0.f, 0.f, 0.f, 0.f};

    // prologue: stage chunk 0 into buf 0
    {
        const float4 xv = *(const float4*)(xsrc);
        F4H8 whv, wlv;
        whv.f = *(const float4*)(wt_hi + (size_t)tid * 8);
        wlv.f = *(const float4*)(wt_lo + (size_t)tid * 8);
        f16x4 hv, lv;
        hv[0] = (f16)xv.x; lv[0] = (f16)(xv.x - (float)hv[0]);
        hv[1] = (f16)xv.y; lv[1] = (f16)(xv.y - (float)hv[1]);
        hv[2] = (f16)xv.z; lv[2] = (f16)(xv.z - (float)hv[2]);
        hv[3] = (f16)xv.w; lv[3] = (f16)(xv.w - (float)hv[3]);
        *(f16x4*)(XH + xoff) = hv;
        *(f16x4*)(XL + xoff) = lv;
        *(f16x8*)(WH + woff) = whv.h;
        *(f16x8*)(WL + woff) = wlv.h;
    }
    __syncthreads();

    for (int c = 0; c < NCH; ++c) {
        const int buf = c & 1;
        // prefetch chunk c+1 (issue early; consumed after MFMAs)
        float4 nx; F4H8 nwh, nwl;
        const bool pf = (c + 1 < NCH);
        if (pf) {
            nx    = *(const float4*)(xsrc + (c + 1) * BK);
            nwh.f = *(const float4*)(wt_hi + (size_t)(c + 1) * 4096 + (size_t)tid * 8);
            nwl.f = *(const float4*)(wt_lo + (size_t)(c + 1) * 4096 + (size_t)tid * 8);
        }
        // fragments from LDS[buf]
        const f16* xh = XH + buf * 2560;
        const f16* xl = XL + buf * 2560;
        const f16* wh = WH + buf * 5120;
        const f16* wl = WL + buf * 5120;
        f16x8 ah[2], al[2], bh[2], bl[2];
        #pragma unroll
        for (int f = 0; f < 2; ++f) {
            ah[f] = *(const f16x8*)(xh + (arow0 + f * 16) * XP + kgrp);
            al[f] = *(const f16x8*)(xl + (arow0 + f * 16) * XP + kgrp);
            bh[f] = *(const f16x8*)(wh + (bcol0 + f * 16) * WP + kgrp);
            bl[f] = *(const f16x8*)(wl + (bcol0 + f * 16) * WP + kgrp);
        }
        #pragma unroll
        for (int i = 0; i < 2; ++i)
            #pragma unroll
            for (int j = 0; j < 2; ++j) {
                acc[i][j] = __builtin_amdgcn_mfma_f32_16x16x32_f16(ah[i], bh[j], acc[i][j], 0, 0, 0);
                acc[i][j] = __builtin_amdgcn_mfma_f32_16x16x32_f16(al[i], bh[j], acc[i][j], 0, 0, 0);
                acc[i][j] = __builtin_amdgcn_mfma_f32_16x16x32_f16(ah[i], bl[j], acc[i][j], 0, 0, 0);
            }
        // write-late: stage chunk c+1 into the other buffer
        if (pf) {
            const int nb = buf ^ 1;
            f16x4 hv, lv;
            hv[0] = (f16)nx.x; lv[0] = (f16)(nx.x - (float)hv[0]);
            hv[1] = (f16)nx.y; lv[1] = (f16)(nx.y - (float)hv[1]);
            hv[2] = (f16)nx.z; lv[2] = (f16)(nx.z - (float)hv[2]);
            hv[3] = (f16)nx.w; lv[3] = (f16)(nx.w - (float)hv[3]);
            *(f16x4*)(XH + nb * 2560 + xoff) = hv;
            *(f16x4*)(XL + nb * 2560 + xoff) = lv;
            *(f16x8*)(WH + nb * 5120 + woff) = nwh.h;
            *(f16x8*)(WL + nb * 5120 + woff) = nwl.h;
        }
        __syncthreads();
    }

    // ---- epilogue: descale + bias, logits -> LDS (overlay) ----
    #pragma unroll
    for (int i = 0; i < 2; ++i) {
        const int tok = wr * 32 + i * 16 + ((lane >> 4) << 2);
        #pragma unroll
        for (int j = 0; j < 2; ++j) {
            const int col = wc * 32 + j * 16 + (lane & 15);
            const float bias = (col < NEXP) ? br[col] : bn[col - NEXP];
            #pragma unroll
            for (int r = 0; r < 4; ++r)
                LG[col * 65 + tok + r] = acc[i][j][r] * INV_WSCALE + bias;
        }
    }
    __syncthreads();

    // ---- top-2 per token (threads 0..63) ----
    if (tid < BM) {
        const int t = tid;
        const float* ep = eps + (size_t)(m0 + t) * NEXP;
        float v1 = -1e30f, v2 = -1e30f;
        int i1 = 0, i2 = 0;
        for (int e = 0; e < NEXP; ++e) {
            const float r  = LG[e * 65 + t];
            const float nr = LG[(NEXP + e) * 65 + t];
            const float sp = fmaxf(nr, 0.f) + log1pf(expf(-fabsf(nr)));
            const float noisy = fmaf(ep[e], sp, r);
            if (noisy > v1) { v2 = v1; i2 = i1; v1 = noisy; i1 = e; }
            else if (noisy > v2) { v2 = noisy; i2 = e; }
        }
        const float e2 = expf(v2 - v1);
        const float p1 = 1.f / (1.f + e2);
        TK[0 * 64 + t] = p1;
        TK[1 * 64 + t] = e2 * p1;
        TK[2 * 64 + t] = (float)i1;
        TK[3 * 64 + t] = (float)i2;
    }
    __syncthreads();

    // ---- write r_out coalesced (8 floats/thread) ----
    {
        const int t  = tid >> 3;
        const int c8 = (tid & 7) << 3;
        const float p1 = TK[0 * 64 + t], p2 = TK[1 * 64 + t];
        const int i1 = (int)TK[2 * 64 + t], i2 = (int)TK[3 * 64 + t];
        float buf[8];
        #pragma unroll
        for (int j = 0; j < 8; ++j) {
            const int e = c8 + j;
            buf[j] = (e == i1) ? p1 : (e == i2) ? p2 : 0.f;
        }
        float* dst = out_r + (size_t)(m0 + t) * NEXP + c8;
        *(float4*)(dst + 0) = *(float4*)(buf + 0);
        *(float4*)(dst + 4) = *(float4*)(buf + 4);
    }
    if (tid < BM) {
        float2 v = make_float2(TK[2 * 64 + tid], TK[3 * 64 + tid]);
        *(float2*)(out_idx + (size_t)(m0 + tid) * 2) = v;
    }
}

// ---------- fallback: round-1 fused f32 kernel (insurance only) ----------
__global__ __launch_bounds__(256) void router_fused_f32(
    const float* __restrict__ x, const float* __restrict__ eps,
    const float* __restrict__ Wr, const float* __restrict__ br,
    const float* __restrict__ Wn, const float* __restrict__ bn,
    float* __restrict__ out_r, float* __restrict__ out_idx)
{
    __shared__ float xs[BK][BM];
    __shared__ float ws2[BK][128];
    __shared__ float lg[128][BM];
    __shared__ float tk[4][BM];
    const int tid = threadIdx.x;
    const int tx = tid & 15, ty = tid >> 4;
    const int m0 = blockIdx.x * BM;
    float acc[4][8];
    #pragma unroll
    for (int i = 0; i < 4; ++i)
        #pragma unroll
        for (int j = 0; j < 8; ++j) acc[i][j] = 0.f;
    for (int kc = 0; kc < NEMBD; kc += BK) {
        {
            const int tm = tid >> 2, kk = (tid & 3) << 3;
            const float* src = x + (size_t)(m0 + tm) * NEMBD + kc + kk;
            const float4 a = *(const float4*)(src);
            const float4 b = *(const float4*)(src + 4);
            xs[kk+0][tm]=a.x; xs[kk+1][tm]=a.y; xs[kk+2][tm]=a.z; xs[kk+3][tm]=a.w;
            xs[kk+4][tm]=b.x; xs[kk+5][tm]=b.y; xs[kk+6][tm]=b.z; xs[kk+7][tm]=b.w;
        }
        {
            const int kr = tid >> 3, q = tid & 7;
            const float* src = (q < 4)
                ? (Wr + (size_t)(kc + kr) * NEXP + (q << 4))
                : (Wn + (size_t)(kc + kr) * NEXP + ((q - 4) << 4));
            float* dst = &ws2[kr][q << 4];
            #pragma unroll
            for (int j = 0; j < 16; ++j) dst[j] = src[j];
        }
        __syncthreads();
        #pragma unroll
        for (int k = 0; k < BK; ++k) {
            const float4 xv = *(const float4*)&xs[k][ty << 2];
            const float4 wa = *(const float4*)&ws2[k][tx << 3];
            const float4 wb = *(const float4*)&ws2[k][(tx << 3) + 4];
            const float xr[4] = {xv.x, xv.y, xv.z, xv.w};
            const float wcx[8] = {wa.x, wa.y, wa.z, wa.w, wb.x, wb.y, wb.z, wb.w};
            #pragma unroll
            for (int i = 0; i < 4; ++i)
                #pragma unroll
                for (int j = 0; j < 8; ++j)
                    acc[i][j] = fmaf(xr[i], wcx[j], acc[i][j]);
        }
        __syncthreads();
    }
    {
        const int n0 = tx << 3;
        #pragma unroll
        for (int j = 0; j < 8; ++j) {
            const int n = n0 + j;
            const float b = (n < NEXP) ? br[n] : bn[n - NEXP];
            #pragma unroll
            for (int i = 0; i < 4; ++i)
                lg[n][(ty << 2) + i] = acc[i][j] + b;
        }
    }
    __syncthreads();
    if (tid < BM) {
        const int t = tid;
        const float* ep = eps + (size_t)(m0 + t) * NEXP;
        float v1 = -1e30f, v2 = -1e30f; int i1 = 0, i2 = 0;
        for (int e = 0; e < NEXP; ++e) {
            const float r = lg[e][t], nr = lg[NEXP + e][t];
            const float sp = fmaxf(nr, 0.f) + log1pf(expf(-fabsf(nr)));
            const float noisy = fmaf(ep[e], sp, r);
            if (noisy > v1) { v2=v1; i2=i1; v1=noisy; i1=e; }
            else if (noisy > v2) { v2=noisy; i2=e; }
        }
        const float e2 = expf(v2 - v1);
        const float p1 = 1.f / (1.f + e2);
        tk[0][t]=p1; tk[1][t]=e2*p1; tk[2][t]=(float)i1; tk[3][t]=(float)i2;
    }
    __syncthreads();
    {
        const int t = tid >> 2, c = tid & 3;
        const float p1 = tk[0][t], p2 = tk[1][t];
        const int i1 = (int)tk[2][t], i2 = (int)tk[3][t];
        float buf[16];
        #pragma unroll
        for (int j = 0; j < 16; ++j) {
            const int e = (c << 4) + j;
            buf[j] = (e == i1) ? p1 : (e == i2) ? p2 : 0.f;
        }
        float* dst = out_r + (size_t)(m0 + t) * NEXP + (c << 4);
        *(float4*)(dst+0)=*(float4*)(buf+0); *(float4*)(dst+4)=*(float4*)(buf+4);
        *(float4*)(dst+8)=*(float4*)(buf+8); *(float4*)(dst+12)=*(float4*)(buf+12);
    }
    if (tid < BM) {
        float2 v = make_float2(tk[2][tid], tk[3][tid]);
        *(float2*)(out_idx + (size_t)(m0 + tid) * 2) = v;
    }
}

extern "C" void kernel_launch(void* const* d_in, const int* in_sizes, int n_in,
                              void* d_out, int out_size, void* d_ws, size_t ws_size,
                              hipStream_t stream) {
    const float* x  = (const float*)d_in[0];
    const float* ep = (const float*)d_in[1];
    const float* Wr = (const float*)d_in[2];
    const float* br = (const float*)d_in[3];
    const float* Wn = (const float*)d_in[4];
    const float* bn = (const float*)d_in[5];

    const int T = in_sizes[1] / NEXP;
    float* out_r   = (float*)d_out;
    float* out_idx = (float*)d_out + (size_t)T * NEXP;

    const size_t limb = (size_t)128 * NEMBD * sizeof(f16);   // 512 KB
    if (ws_size >= 2 * limb) {
        f16* wt_hi = (f16*)d_ws;
        f16* wt_lo = wt_hi + (size_t)128 * NEMBD;
        build_wt<<<NCH, 256, 0, stream>>>(Wr, Wn, wt_hi, wt_lo);
        router_fused<<<T / BM, 512, 0, stream>>>(
            x, ep, wt_hi, wt_lo, br, bn, out_r, out_idx);
    } else {
        router_fused_f32<<<T / BM, 256, 0, stream>>>(
            x, ep, Wr, br, Wn, bn, out_r, out_idx);
    }
}